// Round 8
// baseline (131.826 us; speedup 1.0000x reference)
//
#include <hip/hip_runtime.h>
#include <hip/hip_bf16.h>

#define HH 12
#define DD 64
#define NB1 28
#define NB2 52
#define NF 2
#define FB1 56           // NF*NB1
#define FB2 104          // NF*NB2
#define STRIDE_HD 768    // HH*DD
#define SCALEF 0.125f

typedef float f32x4 __attribute__((ext_vector_type(4)));
typedef float f32x16 __attribute__((ext_vector_type(16)));
typedef short bf16x8 __attribute__((ext_vector_type(8)));

#if __has_builtin(__builtin_amdgcn_exp2f)
#define EXP2(x) __builtin_amdgcn_exp2f(x)
#else
#define EXP2(x) __expf((x) * 0.6931471805599453f)
#endif

__device__ __forceinline__ unsigned short f2bf(float x) {
  union { float f; unsigned u; } c; c.f = x;
  unsigned r = c.u + 0x7fffu + ((c.u >> 16) & 1u);
  return (unsigned short)(r >> 16);
}
__device__ __forceinline__ float bf2f(unsigned short u) {
  union { unsigned u32v; float f; } c; c.u32v = ((unsigned)u) << 16; return c.f;
}

// ===========================================================================
// k_proj: 64-row x 64-out projection tiles + rope, outputs key-grouped.
// ===========================================================================
__global__ __launch_bounds__(256, 4)
void k_proj(const float* __restrict__ lk, const float* __restrict__ rq,
            const float* __restrict__ cosb, const float* __restrict__ sinb,
            const float* __restrict__ W_lkk, const float* __restrict__ b_lkk,
            const float* __restrict__ W_rqk, const float* __restrict__ b_rqk,
            const float* __restrict__ W_lkq, const float* __restrict__ b_lkq,
            const float* __restrict__ W_rqq, const float* __restrict__ b_rqq,
            float* __restrict__ Klg, float* __restrict__ Krg,
            float* __restrict__ ql, float* __restrict__ qr) {
  __shared__ __align__(16) float Wt[64][68];   // [d][e]
  __shared__ __align__(16) float xs[64][68];   // [r][d]
  __shared__ int srows[64];
  __shared__ int obase[64];

  const int tid = threadIdx.x;
  int bx = blockIdx.x;
  int path, h, c;
  if (bx < 552)       { path = 0; h = bx / 46; c = bx % 46; }
  else if (bx < 1104) { path = 1; bx -= 552;  h = bx / 46; c = bx % 46; }
  else if (bx < 1116) { path = 2; h = bx - 1104; c = 0; }
  else                { path = 3; bx -= 1116; h = bx >> 1; c = bx & 1; }

  const float* X  = (path == 1 || path == 3) ? rq : lk;
  const float* W  = (path == 0) ? W_lkk : (path == 1) ? W_rqk : (path == 2) ? W_lkq : W_rqq;
  const float* bb = (path == 0) ? b_lkk : (path == 1) ? b_rqk : (path == 2) ? b_lkq : b_rqq;
  float* out      = (path == 0) ? Klg : (path == 1) ? Krg : (path == 2) ? ql : qr;
  const int nrows = (path == 0 || path == 1) ? ((c == 45) ? 32 : 64)
                   : (path == 2) ? 56 : ((c == 1) ? 40 : 64);

  for (int idx = tid; idx < 4096; idx += 256)
    Wt[idx & 63][idx >> 6] = W[(size_t)h * 4096 + idx];
  if (tid < 64) {
    int rr = tid, s = 0, ob = 0;
    if (rr < nrows) {
      if (path == 0) {
        s = c * 64 + rr;
        int f = s / 1456, rem = s % 1456, b1 = rem / 52, b2 = rem % 52;
        ob = ((h * 56 + f * 28 + b1) * 52 + b2) * 64;
      } else if (path == 1) {
        s = c * 64 + rr;
        int f = s / 1456, rem = s % 1456, b1 = rem / 52, jj = rem % 52;
        ob = ((h * 104 + f * 52 + jj) * 28 + b1) * 64;
      } else if (path == 2) {
        int q = rr;
        s = (q / 28) * 1456 + (q % 28) * 52;
        ob = (h * 56 + q) * 64;
      } else {
        int q = c * 64 + rr;
        s = (q / 52) * 1456 + (q % 52);
        ob = (h * 104 + q) * 64;
      }
    }
    srows[rr] = s; obase[rr] = ob;
  }
  __syncthreads();
  for (int idx = tid; idx < 4096; idx += 256) {
    int r = idx >> 6, d = idx & 63;
    xs[r][d] = X[(size_t)srows[r] * STRIDE_HD + h * DD + d];
  }
  __syncthreads();

  const int it = tid >> 4, kt = tid & 15;
  f32x4 acc0 = {0,0,0,0}, acc1 = {0,0,0,0}, acc2 = {0,0,0,0}, acc3 = {0,0,0,0};
  #pragma unroll 4
  for (int d4 = 0; d4 < 16; ++d4) {
    f32x4 x0 = *(const f32x4*)&xs[4 * it][4 * d4];
    f32x4 x1 = *(const f32x4*)&xs[4 * it + 1][4 * d4];
    f32x4 x2 = *(const f32x4*)&xs[4 * it + 2][4 * d4];
    f32x4 x3 = *(const f32x4*)&xs[4 * it + 3][4 * d4];
    #pragma unroll
    for (int dd = 0; dd < 4; ++dd) {
      f32x4 wv = *(const f32x4*)&Wt[4 * d4 + dd][4 * kt];
      acc0 += x0[dd] * wv;
      acc1 += x1[dd] * wv;
      acc2 += x2[dd] * wv;
      acc3 += x3[dd] * wv;
    }
  }

  f32x4 bv;
  bv[0] = bb[h * 64 + 4 * kt];     bv[1] = bb[h * 64 + 4 * kt + 1];
  bv[2] = bb[h * 64 + 4 * kt + 2]; bv[3] = bb[h * 64 + 4 * kt + 3];
  #pragma unroll
  for (int rr = 0; rr < 4; ++rr) {
    int row = 4 * it + rr;
    if (row < nrows) {
      f32x4 o = (rr == 0) ? acc0 : (rr == 1) ? acc1 : (rr == 2) ? acc2 : acc3;
      o += bv;
      int s = srows[row];
      float c0 = cosb[s * 32 + 2 * kt],     s0 = sinb[s * 32 + 2 * kt];
      float c1 = cosb[s * 32 + 2 * kt + 1], s1 = sinb[s * 32 + 2 * kt + 1];
      f32x4 res;
      res[0] = o[0] * c0 - o[1] * s0;
      res[1] = o[1] * c0 + o[0] * s0;
      res[2] = o[2] * c1 - o[3] * s1;
      res[3] = o[3] * c1 + o[2] * s1;
      *(f32x4*)(out + obase[row] + 4 * kt) = res;
    }
  }
}

// ===========================================================================
// k_sv: per-(n,h) tiny SDPA (wide phases) for both paths + V bf16 re-layout
// ===========================================================================
struct SvShared {
  union {
    struct { float qv[64]; float sc[64]; float ps[64]; float ys[64]; float oe[64]; } s;
    float tile[52][68];
  } u;
};

template<int NK, int NG, int GD, int GMUL, int KSTR>
__device__ void sdpa_path(int n, int h, const float* __restrict__ X,
                          const float* __restrict__ Kg, const float* __restrict__ qb,
                          const float* __restrict__ cosb, const float* __restrict__ sinb,
                          const float* __restrict__ Wv, const float* __restrict__ bvv,
                          float* __restrict__ outb, SvShared& sm) {
  const int t = threadIdx.x;
  const int f = n / GD, g = n % GD;
  const int s_base = f * (NB1 * NB2) + g * GMUL;

  if (t < 64) sm.u.s.qv[t] = qb[(size_t)(h * NG + n) * 64 + t];
  __syncthreads();

  if (t < NK * 4) {
    int r = t >> 2, part = t & 3;
    const float4* kr = (const float4*)(Kg + ((size_t)(h * NG + n) * NK + r) * 64 + part * 16);
    const float4* q4 = (const float4*)(sm.u.s.qv + part * 16);
    float p = 0.f;
    #pragma unroll
    for (int i = 0; i < 4; ++i) {
      float4 kv = kr[i], qv4 = q4[i];
      p += kv.x * qv4.x + kv.y * qv4.y + kv.z * qv4.z + kv.w * qv4.w;
    }
    p += __shfl_xor(p, 1); p += __shfl_xor(p, 2);
    if (part == 0) sm.u.s.sc[r] = p * SCALEF;
  }
  __syncthreads();

  if (t < 64) {
    float v = (t < NK) ? sm.u.s.sc[t] : -1e30f;
    float mx = v;
    for (int o = 32; o; o >>= 1) mx = fmaxf(mx, __shfl_xor(mx, o));
    float e = (t < NK) ? __expf(v - mx) : 0.f;
    float sum = e;
    for (int o = 32; o; o >>= 1) sum += __shfl_xor(sum, o);
    sm.u.s.ps[t] = (t < NK) ? e / sum : 0.f;
  }
  __syncthreads();

  {
    int d = t >> 2, g4 = t & 3;
    constexpr int RPG = NK / 4;
    float yp = 0.f;
    #pragma unroll 4
    for (int rr = 0; rr < RPG; ++rr) {
      int r = g4 * RPG + rr;
      yp += sm.u.s.ps[r] * X[(size_t)(s_base + r * KSTR) * STRIDE_HD + h * DD + d];
    }
    yp += __shfl_xor(yp, 1); yp += __shfl_xor(yp, 2);
    if (g4 == 0) sm.u.s.ys[d] = yp;
  }
  __syncthreads();

  {
    int e = t >> 2, part = t & 3;
    const float4* wr = (const float4*)(Wv + (size_t)h * 4096 + e * 64 + part * 16);
    const float4* y4 = (const float4*)(sm.u.s.ys + part * 16);
    float p = 0.f;
    #pragma unroll
    for (int i = 0; i < 4; ++i) {
      float4 wv = wr[i], yv = y4[i];
      p += wv.x * yv.x + wv.y * yv.y + wv.z * yv.z + wv.w * yv.w;
    }
    p += __shfl_xor(p, 1); p += __shfl_xor(p, 2);
    if (part == 0) sm.u.s.oe[e] = p + bvv[h * 64 + e];
  }
  __syncthreads();

  if (t < 32) {
    float co = cosb[s_base * 32 + t], si = sinb[s_base * 32 + t];
    float o0 = sm.u.s.oe[2 * t], o1 = sm.u.s.oe[2 * t + 1];
    outb[(size_t)n * STRIDE_HD + h * DD + 2 * t]     = o0 * co - o1 * si;
    outb[(size_t)n * STRIDE_HD + h * DD + 2 * t + 1] = o1 * co + o0 * si;
  }
}

// v (S,H,D) f32 -> vb2[h][fk][l8][d][li] bf16 (l = l8*8+li, l>=52 zero)
__device__ void vb_path(int fk, int h, const float* __restrict__ v,
                        unsigned short* __restrict__ vb2, SvShared& sm) {
  const int tid = threadIdx.x;
  for (int idx = tid; idx < NB2 * DD; idx += 256) {
    int l = idx >> 6, d = idx & 63;
    sm.u.tile[l][d] = v[(size_t)(fk * NB2 + l) * STRIDE_HD + h * DD + d];
  }
  __syncthreads();
  for (int idx = tid; idx < 512; idx += 256) {
    int l8 = idx >> 6, d = idx & 63;
    unsigned short tmp[8];
    #pragma unroll
    for (int li = 0; li < 8; ++li) {
      int l = l8 * 8 + li;
      tmp[li] = (l < NB2) ? f2bf(sm.u.tile[l][d]) : (unsigned short)0;
    }
    bf16x8* dst = (bf16x8*)(vb2 + (((size_t)(h * FB1 + fk) * 8 + l8) * 64 + d) * 8);
    *dst = *(bf16x8*)tmp;
  }
}

__global__ __launch_bounds__(256)
void k_sv(const float* __restrict__ lk, const float* __restrict__ rq,
          const float* __restrict__ v,
          const float* __restrict__ cosb, const float* __restrict__ sinb,
          const float* __restrict__ Klg, const float* __restrict__ Krg,
          const float* __restrict__ ql, const float* __restrict__ qr,
          const float* __restrict__ W_lkv, const float* __restrict__ b_lkv,
          const float* __restrict__ W_rqv, const float* __restrict__ b_rqv,
          float* __restrict__ lk_out, float* __restrict__ rq_out,
          unsigned short* __restrict__ vb2) {
  __shared__ SvShared sm;
  const int bx = blockIdx.x;
  if (bx < 672) {
    sdpa_path<52, 56, 28, 52, 1>(bx % 56, bx / 56, lk, Klg, ql, cosb, sinb,
                                 W_lkv, b_lkv, lk_out, sm);
  } else if (bx < 1920) {
    int id = bx - 672;
    sdpa_path<28, 104, 52, 1, 52>(id % 104, id / 104, rq, Krg, qr, cosb, sinb,
                                  W_rqv, b_rqv, rq_out, sm);
  } else {
    int id = bx - 1920;
    vb_path(id % 56, id / 56, v, vb2, sm);
  }
}

// ===========================================================================
// MID (MFMA, hi/lo bf16 split = fp32-accurate):
// C[P=2912][Q] = sum_d rope(X)[P,d] * Y[Q,d], K=64.
// PATH 0 (L): X=lq, Y=lk_out (56 rows, QROWS=64),  out=Lbuf scatter
// PATH 1 (R): X=rk, Y=rq_out (104 rows, QROWS=128), out=Rbuf col=P
// Block = (h, 224-row chunk of P), 7 X-tiles of 32; wave w owns Q-tile w.
// LDS swizzle: k ^= (row&7)<<3 (bf16 units) on both write and read.
// ===========================================================================
template<int QROWS, int QV, int NTHR, int PATH>
__global__ __launch_bounds__(NTHR)
void k_midg(const float* __restrict__ X, const float* __restrict__ Yb,
            const float* __restrict__ cosb, const float* __restrict__ sinb,
            float* __restrict__ outb) {
  const int bx = blockIdx.x;
  const int h = bx / 13, chunk = bx % 13;
  const int tid = threadIdx.x;
  const int lane = tid & 63;
  const int qt = tid >> 6;            // wave = Q-tile
  const int hi = lane >> 5;
  const int arow = lane & 31;

  __shared__ __align__(16) unsigned short Yhi[QROWS][64];
  __shared__ __align__(16) unsigned short Ylo[QROWS][64];
  __shared__ __align__(16) unsigned short Xhi[32][64];
  __shared__ __align__(16) unsigned short Xlo[32][64];

  // ---- stage Y hi/lo (swizzled), rows >= QV zero ----
  for (int idx = tid; idx < QROWS * 32; idx += NTHR) {
    int q = idx >> 5, m = idx & 31;
    float y0 = 0.f, y1 = 0.f;
    if (q < QV) {
      float2 yv = *(const float2*)(Yb + (size_t)q * STRIDE_HD + h * DD + 2 * m);
      y0 = yv.x; y1 = yv.y;
    }
    unsigned short h0 = f2bf(y0), h1 = f2bf(y1);
    unsigned short l0 = f2bf(y0 - bf2f(h0)), l1 = f2bf(y1 - bf2f(h1));
    int ms = m ^ ((q & 7) << 2);
    ((unsigned*)Yhi[q])[ms] = (unsigned)h0 | ((unsigned)h1 << 16);
    ((unsigned*)Ylo[q])[ms] = (unsigned)l0 | ((unsigned)l1 << 16);
  }
  __syncthreads();

  // ---- hoist B fragments (loop-invariant) ----
  bf16x8 Bhi[4], Blo[4];
  {
    const int brow = qt * 32 + arow;
    const int bswz = (brow & 7) << 3;
    #pragma unroll
    for (int ks = 0; ks < 4; ++ks) {
      int kb = (ks * 16 + hi * 8) ^ bswz;
      Bhi[ks] = *(const bf16x8*)&Yhi[brow][kb];
      Blo[ks] = *(const bf16x8*)&Ylo[brow][kb];
    }
  }

  for (int t = 0; t < 7; ++t) {
    const int rowbase = (chunk * 7 + t) * 32;
    // ---- stage rope'd X tile hi/lo (swizzled) ----
    for (int pidx = tid; pidx < 1024; pidx += NTHR) {
      int r = pidx >> 5, m = pidx & 31;
      int srow = rowbase + r;
      float2 xv = *(const float2*)(X + (size_t)srow * STRIDE_HD + h * DD + 2 * m);
      float co = cosb[srow * 32 + m], si = sinb[srow * 32 + m];
      float o0 = xv.x * co - xv.y * si;
      float o1 = xv.y * co + xv.x * si;
      unsigned short h0 = f2bf(o0), h1 = f2bf(o1);
      unsigned short l0 = f2bf(o0 - bf2f(h0)), l1 = f2bf(o1 - bf2f(h1));
      int ms = m ^ ((r & 7) << 2);
      ((unsigned*)Xhi[r])[ms] = (unsigned)h0 | ((unsigned)h1 << 16);
      ((unsigned*)Xlo[r])[ms] = (unsigned)l0 | ((unsigned)l1 << 16);
    }
    __syncthreads();

    // ---- 12 MFMA (hi*hi + hi*lo + lo*hi) ----
    f32x16 acc = {0.f,0.f,0.f,0.f,0.f,0.f,0.f,0.f,0.f,0.f,0.f,0.f,0.f,0.f,0.f,0.f};
    {
      const int aswz = (arow & 7) << 3;
      #pragma unroll
      for (int ks = 0; ks < 4; ++ks) {
        int kb = (ks * 16 + hi * 8) ^ aswz;
        bf16x8 Ahi = *(const bf16x8*)&Xhi[arow][kb];
        bf16x8 Alo = *(const bf16x8*)&Xlo[arow][kb];
        acc = __builtin_amdgcn_mfma_f32_32x32x16_bf16(Ahi, Bhi[ks], acc, 0, 0, 0);
        acc = __builtin_amdgcn_mfma_f32_32x32x16_bf16(Ahi, Blo[ks], acc, 0, 0, 0);
        acc = __builtin_amdgcn_mfma_f32_32x32x16_bf16(Alo, Bhi[ks], acc, 0, 0, 0);
      }
    }

    // ---- write C tile ----
    if (PATH == 0) {
      int col = qt * 32 + arow;                       // (f,k)
      if (col < 56) {
        int f = (col >= 28) ? 1 : 0;
        int k = col - f * 28;
        #pragma unroll
        for (int rg = 0; rg < 16; ++rg) {
          int P = rowbase + (rg & 3) + 8 * (rg >> 2) + 4 * hi;
          int a = (P >= 1456) ? 1 : 0;
          int rem2 = P - a * 1456;
          int i = rem2 / 52, j = rem2 - i * 52;
          outb[((size_t)(h * 104 + a * 52 + j)) * 1568 + f * 784 + i * 28 + k] = acc[rg];
        }
      }
    } else {
      int cq = qt * 32 + arow;                        // (aa,jj)
      if (cq < 104) {
        int aa = (cq >= 52) ? 1 : 0;
        int jj = cq - aa * 52;
        float* rowp = outb + ((size_t)((h * 2 + aa) * 52 + jj)) * 2912 + rowbase + 4 * hi;
        #pragma unroll
        for (int q4 = 0; q4 < 4; ++q4) {
          f32x4 res = {acc[4 * q4], acc[4 * q4 + 1], acc[4 * q4 + 2], acc[4 * q4 + 3]};
          *(f32x4*)(rowp + 8 * q4) = res;
        }
      }
    }
    __syncthreads();   // protect Xhi/Xlo before next stage
  }
}

// ===========================================================================
// MAIN: factorized flash attention. 4 waves = 4 fk-segments; each wave
// computes P once and does 2 MFMAs (both d-halves). No in-loop barriers.
// ===========================================================================
struct MainPro { float Ls2T[2][28][36]; float Rs[56][64]; };
union MainShared { MainPro p; float epil[4][16][64]; };

__global__ __launch_bounds__(256, 4)
void k_main(const float* __restrict__ Lbuf, const float* __restrict__ Rbuf,
            const unsigned short* __restrict__ vb2, float* __restrict__ outp) {
  const int bid0 = blockIdx.x;
  const int bid = (bid0 & 7) * 156 + (bid0 >> 3);   // 1248 = 8*156, XCD-chunked
  const int h = bid / (NF * NB2);
  const int rem = bid % (NF * NB2);
  const int a = rem / NB2, j = rem % NB2;
  const int tid = threadIdx.x;
  const int lane = tid & 63;
  const int w = tid >> 6;

  __shared__ __align__(16) MainShared ms;
  __shared__ float m2s[32], Rmx[FB1], Rmn[FB1], els[4][32];

  const float SC = SCALEF * 1.44269504f;
  for (int idx = tid; idx < NF * NB1 * NB1; idx += 256) {
    int ff = idx / 784, r2 = idx % 784;
    int i = r2 / 28, kk = r2 % 28;
    ms.p.Ls2T[ff][kk][i] = Lbuf[(size_t)bid * (NF * NB1 * NB1) + idx] * SC;
  }
  if (tid < 224) {                                    // zero pad rows i=28..31
    int ff = tid / 112, r2 = tid % 112;
    ms.p.Ls2T[ff][r2 >> 2][28 + (r2 & 3)] = 0.f;
  }
  for (int idx = tid; idx < FB1 * 13; idx += 256) {
    int fk = idx / 13, lc = idx % 13;
    float4 vv = ((const float4*)(Rbuf + (size_t)bid * (NF * NB1 * NB2)))[idx];
    *(float4*)&ms.p.Rs[fk][lc * 4] = vv;
  }
  if (tid >= 252) m2s[tid - 224] = 0.f;               // pad rows 28..31
  __syncthreads();

  if (tid < 224) {                                    // col max/min of R
    int fk = tid >> 2, part = tid & 3;
    float mx = -1e30f, mn = 1e30f;
    for (int l = part * 13; l < part * 13 + 13; ++l) {
      float x = ms.p.Rs[fk][l];
      mx = fmaxf(mx, x); mn = fminf(mn, x);
    }
    mx = fmaxf(mx, __shfl_xor(mx, 1)); mn = fminf(mn, __shfl_xor(mn, 1));
    mx = fmaxf(mx, __shfl_xor(mx, 2)); mn = fminf(mn, __shfl_xor(mn, 2));
    if (part == 0) { Rmx[fk] = mx; Rmn[fk] = mn; }
  }
  __syncthreads();

  if (tid < 224) {                                    // exact row max (log2 units)
    int i = tid >> 3, s = tid & 7;
    float m = -1e30f;
    #pragma unroll
    for (int n = 0; n < 7; ++n) {
      int fk = s + 8 * n;
      int ff = (fk >= NB1) ? 1 : 0, kk = fk - ff * NB1;
      float Lv = ms.p.Ls2T[ff][kk][i];
      m = fmaxf(m, fmaxf(Lv * Rmx[fk], Lv * Rmn[fk]));
    }
    m = fmaxf(m, __shfl_xor(m, 1));
    m = fmaxf(m, __shfl_xor(m, 2));
    m = fmaxf(m, __shfl_xor(m, 4));
    if (s == 0) m2s[i] = m;
  }
  __syncthreads();

  const int row = lane & 31;
  const int hi = lane >> 5;
  const float nm = -m2s[row];
  // vb2 layout: [h][fk][l8][d][li], bf16x8 granule index = fk*512 + l8*64 + d
  const bf16x8* vw = (const bf16x8*)vb2 + (size_t)h * 28672 + hi * 64 + row;

  f32x16 acc0 = {0.f,0.f,0.f,0.f,0.f,0.f,0.f,0.f,0.f,0.f,0.f,0.f,0.f,0.f,0.f,0.f};
  f32x16 acc1 = {0.f,0.f,0.f,0.f,0.f,0.f,0.f,0.f,0.f,0.f,0.f,0.f,0.f,0.f,0.f,0.f};
  float lsum = 0.f;

  for (int t = 0; t < 14; ++t) {
    const int fk = w * 14 + t;
    const float Lv = ms.p.Ls2T[w >> 1][(w & 1) * 14 + t][row];
    const bf16x8* vp = vw + (size_t)fk * 512;
    #pragma unroll
    for (int ks = 0; ks < 4; ++ks) {
      const int k0 = ks * 16 + hi * 8;
      float4 ra = *(const float4*)&ms.p.Rs[fk][k0];
      float4 rb = *(const float4*)&ms.p.Rs[fk][k0 + 4];
      float p0 = EXP2(fmaf(Lv, ra.x, nm));
      float p1 = EXP2(fmaf(Lv, ra.y, nm));
      float p2 = EXP2(fmaf(Lv, ra.z, nm));
      float p3 = EXP2(fmaf(Lv, ra.w, nm));
      float p4 = EXP2(fmaf(Lv, rb.x, nm));
      float p5 = EXP2(fmaf(Lv, rb.y, nm));
      float p6 = EXP2(fmaf(Lv, rb.z, nm));
      float p7 = EXP2(fmaf(Lv, rb.w, nm));
      if (ks == 3) {                                  // l = 48+hi*8+idx; mask l>=52
        if (hi == 0) { p4 = 0.f; p5 = 0.f; p6 = 0.f; p7 = 0.f; }
        else { p0 = 0.f; p1 = 0.f; p2 = 0.f; p3 = 0.f;
               p4 = 0.f; p5 = 0.f; p6 = 0.f; p7 = 0.f; }
      }
      lsum += ((p0 + p1) + (p2 + p3)) + ((p4 + p5) + (p6 + p7));
      union { bf16x8 v8; __hip_bfloat162 h2[4]; } pk;
      pk.h2[0] = __float22bfloat162_rn(make_float2(p0, p1));
      pk.h2[1] = __float22bfloat162_rn(make_float2(p2, p3));
      pk.h2[2] = __float22bfloat162_rn(make_float2(p4, p5));
      pk.h2[3] = __float22bfloat162_rn(make_float2(p6, p7));
      bf16x8 b0 = vp[ks * 128];
      bf16x8 b1 = vp[ks * 128 + 32];
      acc0 = __builtin_amdgcn_mfma_f32_32x32x16_bf16(pk.v8, b0, acc0, 0, 0, 0);
      acc1 = __builtin_amdgcn_mfma_f32_32x32x16_bf16(pk.v8, b1, acc1, 0, 0, 0);
    }
  }

  lsum += __shfl_xor(lsum, 32);
  if (lane < 32) els[w][lane] = lsum;
  __syncthreads();                                     // Rs/Ls2T reads done; els visible

  // epilogue: 2 rounds (d-halves) of 4-segment reduction through LDS
  #pragma unroll
  for (int half = 0; half < 2; ++half) {
    if (half) __syncthreads();
    #pragma unroll
    for (int r = 0; r < 16; ++r)
      ms.epil[w][r][lane] = half ? acc1[r] : acc0[r];
    __syncthreads();
    #pragma unroll
    for (int q = 0; q < 4; ++q) {
      int r = (tid >> 6) + q * 4;
      int elane = tid & 63;
      float val = ms.epil[0][r][elane] + ms.epil[1][r][elane]
                + ms.epil[2][r][elane] + ms.epil[3][r][elane];
      int irow = (r & 3) + 8 * (r >> 2) + 4 * (elane >> 5);
      if (irow < NB1) {
        float li = 1.0f / (els[0][irow] + els[1][irow] + els[2][irow] + els[3][irow]);
        int srow = a * (NB1 * NB2) + irow * NB2 + j;
        int d = half * 32 + (elane & 31);
        outp[(size_t)srow * STRIDE_HD + h * DD + d] = val * li;
      }
    }
  }
}

// ---------------------------------------------------------------------------
extern "C" void kernel_launch(void* const* d_in, const int* in_sizes, int n_in,
                              void* d_out, int out_size, void* d_ws, size_t ws_size,
                              hipStream_t stream) {
  (void)in_sizes; (void)n_in; (void)out_size; (void)ws_size;
  const float* lq   = (const float*)d_in[0];
  const float* lk   = (const float*)d_in[1];
  const float* rq   = (const float*)d_in[2];
  const float* rk   = (const float*)d_in[3];
  const float* v    = (const float*)d_in[4];
  const float* cosb = (const float*)d_in[5];
  const float* sinb = (const float*)d_in[6];
  const float* W_lkq = (const float*)d_in[7];  const float* b_lkq = (const float*)d_in[8];
  const float* W_lkk = (const float*)d_in[9];  const float* b_lkk = (const float*)d_in[10];
  const float* W_lkv = (const float*)d_in[11]; const float* b_lkv = (const float*)d_in[12];
  const float* W_rqq = (const float*)d_in[13]; const float* b_rqq = (const float*)d_in[14];
  const float* W_rqk = (const float*)d_in[15]; const float* b_rqk = (const float*)d_in[16];
  const float* W_rqv = (const float*)d_in[17]; const float* b_rqv = (const float*)d_in[18];

  float* ws = (float*)d_ws;
  float* lk_out = ws;                                   // 43008
  float* rq_out = ws + 43008;                           // 79872
  float* Lbuf   = ws + 122880;                          // 1956864
  float* Rbuf   = ws + 2079744;                         // 3634176
  unsigned short* vb2 = (unsigned short*)(ws + 5713920);// 2752512 shorts
  float* ql     = ws + 7090176;                         // 43008
  float* qr     = ws + 7133184;                         // 79872
  // Klg/Krg alias the Lbuf/Rbuf space (dead before k_mid writes them)
  float* Klg = Lbuf;                                    // 2236416
  float* Krg = Lbuf + 2236416;                          // 2236416 (ends < Rbuf end)

  k_proj<<<1140, 256, 0, stream>>>(lk, rq, cosb, sinb,
      W_lkk, b_lkk, W_rqk, b_rqk, W_lkq, b_lkq, W_rqq, b_rqq,
      Klg, Krg, ql, qr);
  k_sv<<<2592, 256, 0, stream>>>(lk, rq, v, cosb, sinb, Klg, Krg, ql, qr,
      W_lkv, b_lkv, W_rqv, b_rqv, lk_out, rq_out, vb2);
  k_midg<64, 56, 128, 0><<<156, 128, 0, stream>>>(lq, lk_out, cosb, sinb, Lbuf);
  k_midg<128, 104, 256, 1><<<156, 256, 0, stream>>>(rk, rq_out, cosb, sinb, Rbuf);
  k_main<<<1248, 256, 0, stream>>>(Lbuf, Rbuf, vb2, (float*)d_out);
}

// Round 9
// 113.479 us; speedup vs baseline: 1.1617x; 1.1617x over previous
//
#include <hip/hip_runtime.h>
#include <hip/hip_bf16.h>

#define HH 12
#define DD 64
#define NB1 28
#define NB2 52
#define NF 2
#define FB1 56           // NF*NB1
#define FB2 104          // NF*NB2
#define STRIDE_HD 768    // HH*DD
#define SCALEF 0.125f

typedef float f32x4 __attribute__((ext_vector_type(4)));
typedef float f32x16 __attribute__((ext_vector_type(16)));
typedef short bf16x8 __attribute__((ext_vector_type(8)));

#if __has_builtin(__builtin_amdgcn_exp2f)
#define EXP2(x) __builtin_amdgcn_exp2f(x)
#else
#define EXP2(x) __expf((x) * 0.6931471805599453f)
#endif

__device__ __forceinline__ unsigned short f2bf(float x) {
  union { float f; unsigned u; } c; c.f = x;
  unsigned r = c.u + 0x7fffu + ((c.u >> 16) & 1u);
  return (unsigned short)(r >> 16);
}
__device__ __forceinline__ float bf2f(unsigned short u) {
  union { unsigned u32v; float f; } c; c.u32v = ((unsigned)u) << 16; return c.f;
}

// ===========================================================================
// k_proj: 64-row x 64-out projection tiles + rope, outputs key-grouped.
// ===========================================================================
__global__ __launch_bounds__(256, 4)
void k_proj(const float* __restrict__ lk, const float* __restrict__ rq,
            const float* __restrict__ cosb, const float* __restrict__ sinb,
            const float* __restrict__ W_lkk, const float* __restrict__ b_lkk,
            const float* __restrict__ W_rqk, const float* __restrict__ b_rqk,
            const float* __restrict__ W_lkq, const float* __restrict__ b_lkq,
            const float* __restrict__ W_rqq, const float* __restrict__ b_rqq,
            float* __restrict__ Klg, float* __restrict__ Krg,
            float* __restrict__ ql, float* __restrict__ qr) {
  __shared__ __align__(16) float Wt[64][68];   // [d][e]
  __shared__ __align__(16) float xs[64][68];   // [r][d]
  __shared__ int srows[64];
  __shared__ int obase[64];

  const int tid = threadIdx.x;
  int bx = blockIdx.x;
  int path, h, c;
  if (bx < 552)       { path = 0; h = bx / 46; c = bx % 46; }
  else if (bx < 1104) { path = 1; bx -= 552;  h = bx / 46; c = bx % 46; }
  else if (bx < 1116) { path = 2; h = bx - 1104; c = 0; }
  else                { path = 3; bx -= 1116; h = bx >> 1; c = bx & 1; }

  const float* X  = (path == 1 || path == 3) ? rq : lk;
  const float* W  = (path == 0) ? W_lkk : (path == 1) ? W_rqk : (path == 2) ? W_lkq : W_rqq;
  const float* bb = (path == 0) ? b_lkk : (path == 1) ? b_rqk : (path == 2) ? b_lkq : b_rqq;
  float* out      = (path == 0) ? Klg : (path == 1) ? Krg : (path == 2) ? ql : qr;
  const int nrows = (path == 0 || path == 1) ? ((c == 45) ? 32 : 64)
                   : (path == 2) ? 56 : ((c == 1) ? 40 : 64);

  for (int idx = tid; idx < 4096; idx += 256)
    Wt[idx & 63][idx >> 6] = W[(size_t)h * 4096 + idx];
  if (tid < 64) {
    int rr = tid, s = 0, ob = 0;
    if (rr < nrows) {
      if (path == 0) {
        s = c * 64 + rr;
        int f = s / 1456, rem = s % 1456, b1 = rem / 52, b2 = rem % 52;
        ob = ((h * 56 + f * 28 + b1) * 52 + b2) * 64;
      } else if (path == 1) {
        s = c * 64 + rr;
        int f = s / 1456, rem = s % 1456, b1 = rem / 52, jj = rem % 52;
        ob = ((h * 104 + f * 52 + jj) * 28 + b1) * 64;
      } else if (path == 2) {
        int q = rr;
        s = (q / 28) * 1456 + (q % 28) * 52;
        ob = (h * 56 + q) * 64;
      } else {
        int q = c * 64 + rr;
        s = (q / 52) * 1456 + (q % 52);
        ob = (h * 104 + q) * 64;
      }
    }
    srows[rr] = s; obase[rr] = ob;
  }
  __syncthreads();
  for (int idx = tid; idx < 4096; idx += 256) {
    int r = idx >> 6, d = idx & 63;
    xs[r][d] = X[(size_t)srows[r] * STRIDE_HD + h * DD + d];
  }
  __syncthreads();

  const int it = tid >> 4, kt = tid & 15;
  f32x4 acc0 = {0,0,0,0}, acc1 = {0,0,0,0}, acc2 = {0,0,0,0}, acc3 = {0,0,0,0};
  #pragma unroll 4
  for (int d4 = 0; d4 < 16; ++d4) {
    f32x4 x0 = *(const f32x4*)&xs[4 * it][4 * d4];
    f32x4 x1 = *(const f32x4*)&xs[4 * it + 1][4 * d4];
    f32x4 x2 = *(const f32x4*)&xs[4 * it + 2][4 * d4];
    f32x4 x3 = *(const f32x4*)&xs[4 * it + 3][4 * d4];
    #pragma unroll
    for (int dd = 0; dd < 4; ++dd) {
      f32x4 wv = *(const f32x4*)&Wt[4 * d4 + dd][4 * kt];
      acc0 += x0[dd] * wv;
      acc1 += x1[dd] * wv;
      acc2 += x2[dd] * wv;
      acc3 += x3[dd] * wv;
    }
  }

  f32x4 bv;
  bv[0] = bb[h * 64 + 4 * kt];     bv[1] = bb[h * 64 + 4 * kt + 1];
  bv[2] = bb[h * 64 + 4 * kt + 2]; bv[3] = bb[h * 64 + 4 * kt + 3];
  #pragma unroll
  for (int rr = 0; rr < 4; ++rr) {
    int row = 4 * it + rr;
    if (row < nrows) {
      f32x4 o = (rr == 0) ? acc0 : (rr == 1) ? acc1 : (rr == 2) ? acc2 : acc3;
      o += bv;
      int s = srows[row];
      float c0 = cosb[s * 32 + 2 * kt],     s0 = sinb[s * 32 + 2 * kt];
      float c1 = cosb[s * 32 + 2 * kt + 1], s1 = sinb[s * 32 + 2 * kt + 1];
      f32x4 res;
      res[0] = o[0] * c0 - o[1] * s0;
      res[1] = o[1] * c0 + o[0] * s0;
      res[2] = o[2] * c1 - o[3] * s1;
      res[3] = o[3] * c1 + o[2] * s1;
      *(f32x4*)(out + obase[row] + 4 * kt) = res;
    }
  }
}

// ===========================================================================
// k_sv: per-(n,h) tiny SDPA (wide phases) for both paths + V bf16 re-layout
// ===========================================================================
struct SvShared {
  union {
    struct { float qv[64]; float sc[64]; float ps[64]; float ys[64]; float oe[64]; } s;
    float tile[52][68];
  } u;
};

template<int NK, int NG, int GD, int GMUL, int KSTR>
__device__ void sdpa_path(int n, int h, const float* __restrict__ X,
                          const float* __restrict__ Kg, const float* __restrict__ qb,
                          const float* __restrict__ cosb, const float* __restrict__ sinb,
                          const float* __restrict__ Wv, const float* __restrict__ bvv,
                          float* __restrict__ outb, SvShared& sm) {
  const int t = threadIdx.x;
  const int f = n / GD, g = n % GD;
  const int s_base = f * (NB1 * NB2) + g * GMUL;

  if (t < 64) sm.u.s.qv[t] = qb[(size_t)(h * NG + n) * 64 + t];
  __syncthreads();

  if (t < NK * 4) {
    int r = t >> 2, part = t & 3;
    const float4* kr = (const float4*)(Kg + ((size_t)(h * NG + n) * NK + r) * 64 + part * 16);
    const float4* q4 = (const float4*)(sm.u.s.qv + part * 16);
    float p = 0.f;
    #pragma unroll
    for (int i = 0; i < 4; ++i) {
      float4 kv = kr[i], qv4 = q4[i];
      p += kv.x * qv4.x + kv.y * qv4.y + kv.z * qv4.z + kv.w * qv4.w;
    }
    p += __shfl_xor(p, 1); p += __shfl_xor(p, 2);
    if (part == 0) sm.u.s.sc[r] = p * SCALEF;
  }
  __syncthreads();

  if (t < 64) {
    float v = (t < NK) ? sm.u.s.sc[t] : -1e30f;
    float mx = v;
    for (int o = 32; o; o >>= 1) mx = fmaxf(mx, __shfl_xor(mx, o));
    float e = (t < NK) ? __expf(v - mx) : 0.f;
    float sum = e;
    for (int o = 32; o; o >>= 1) sum += __shfl_xor(sum, o);
    sm.u.s.ps[t] = (t < NK) ? e / sum : 0.f;
  }
  __syncthreads();

  {
    int d = t >> 2, g4 = t & 3;
    constexpr int RPG = NK / 4;
    float yp = 0.f;
    #pragma unroll 4
    for (int rr = 0; rr < RPG; ++rr) {
      int r = g4 * RPG + rr;
      yp += sm.u.s.ps[r] * X[(size_t)(s_base + r * KSTR) * STRIDE_HD + h * DD + d];
    }
    yp += __shfl_xor(yp, 1); yp += __shfl_xor(yp, 2);
    if (g4 == 0) sm.u.s.ys[d] = yp;
  }
  __syncthreads();

  {
    int e = t >> 2, part = t & 3;
    const float4* wr = (const float4*)(Wv + (size_t)h * 4096 + e * 64 + part * 16);
    const float4* y4 = (const float4*)(sm.u.s.ys + part * 16);
    float p = 0.f;
    #pragma unroll
    for (int i = 0; i < 4; ++i) {
      float4 wv = wr[i], yv = y4[i];
      p += wv.x * yv.x + wv.y * yv.y + wv.z * yv.z + wv.w * yv.w;
    }
    p += __shfl_xor(p, 1); p += __shfl_xor(p, 2);
    if (part == 0) sm.u.s.oe[e] = p + bvv[h * 64 + e];
  }
  __syncthreads();

  if (t < 32) {
    float co = cosb[s_base * 32 + t], si = sinb[s_base * 32 + t];
    float o0 = sm.u.s.oe[2 * t], o1 = sm.u.s.oe[2 * t + 1];
    outb[(size_t)n * STRIDE_HD + h * DD + 2 * t]     = o0 * co - o1 * si;
    outb[(size_t)n * STRIDE_HD + h * DD + 2 * t + 1] = o1 * co + o0 * si;
  }
}

// v (S,H,D) f32 -> vb2[h][fk][l8][d][li] bf16 (l = l8*8+li, l>=52 zero)
__device__ void vb_path(int fk, int h, const float* __restrict__ v,
                        unsigned short* __restrict__ vb2, SvShared& sm) {
  const int tid = threadIdx.x;
  for (int idx = tid; idx < NB2 * DD; idx += 256) {
    int l = idx >> 6, d = idx & 63;
    sm.u.tile[l][d] = v[(size_t)(fk * NB2 + l) * STRIDE_HD + h * DD + d];
  }
  __syncthreads();
  for (int idx = tid; idx < 512; idx += 256) {
    int l8 = idx >> 6, d = idx & 63;
    unsigned short tmp[8];
    #pragma unroll
    for (int li = 0; li < 8; ++li) {
      int l = l8 * 8 + li;
      tmp[li] = (l < NB2) ? f2bf(sm.u.tile[l][d]) : (unsigned short)0;
    }
    bf16x8* dst = (bf16x8*)(vb2 + (((size_t)(h * FB1 + fk) * 8 + l8) * 64 + d) * 8);
    *dst = *(bf16x8*)tmp;
  }
}

__global__ __launch_bounds__(256)
void k_sv(const float* __restrict__ lk, const float* __restrict__ rq,
          const float* __restrict__ v,
          const float* __restrict__ cosb, const float* __restrict__ sinb,
          const float* __restrict__ Klg, const float* __restrict__ Krg,
          const float* __restrict__ ql, const float* __restrict__ qr,
          const float* __restrict__ W_lkv, const float* __restrict__ b_lkv,
          const float* __restrict__ W_rqv, const float* __restrict__ b_rqv,
          float* __restrict__ lk_out, float* __restrict__ rq_out,
          unsigned short* __restrict__ vb2) {
  __shared__ SvShared sm;
  const int bx = blockIdx.x;
  if (bx < 672) {
    sdpa_path<52, 56, 28, 52, 1>(bx % 56, bx / 56, lk, Klg, ql, cosb, sinb,
                                 W_lkv, b_lkv, lk_out, sm);
  } else if (bx < 1920) {
    int id = bx - 672;
    sdpa_path<28, 104, 52, 1, 52>(id % 104, id / 104, rq, Krg, qr, cosb, sinb,
                                  W_rqv, b_rqv, rq_out, sm);
  } else {
    int id = bx - 1920;
    vb_path(id % 56, id / 56, v, vb2, sm);
  }
}

// ===========================================================================
// MID (MFMA, hi/lo bf16 split): ONE 32-row X-tile per block (grid 1092 each).
// PATH 0 (L): X=lq, Y=lk_out  -> LbufN[h][P][col(f,k)] natural, coalesced.
// PATH 1 (R): X=rk, Y=rq_out  -> Rbuf[(h,aa,jj)][P] as before.
// ===========================================================================
template<int QROWS, int QV, int NTHR, int PATH>
__global__ __launch_bounds__(NTHR)
void k_midg(const float* __restrict__ X, const float* __restrict__ Yb,
            const float* __restrict__ cosb, const float* __restrict__ sinb,
            float* __restrict__ outb) {
  const int bx = blockIdx.x;
  const int h = bx / 91, pt = bx % 91;
  const int rowbase = pt * 32;
  const int tid = threadIdx.x;
  const int lane = tid & 63;
  const int qt = tid >> 6;
  const int hi = lane >> 5;
  const int arow = lane & 31;

  __shared__ __align__(16) unsigned short Yhi[QROWS][64];
  __shared__ __align__(16) unsigned short Ylo[QROWS][64];
  __shared__ __align__(16) unsigned short Xhi[32][64];
  __shared__ __align__(16) unsigned short Xlo[32][64];

  // stage Y hi/lo (swizzled), rows >= QV zero
  for (int idx = tid; idx < QROWS * 32; idx += NTHR) {
    int q = idx >> 5, m = idx & 31;
    float y0 = 0.f, y1 = 0.f;
    if (q < QV) {
      float2 yv = *(const float2*)(Yb + (size_t)q * STRIDE_HD + h * DD + 2 * m);
      y0 = yv.x; y1 = yv.y;
    }
    unsigned short h0 = f2bf(y0), h1 = f2bf(y1);
    unsigned short l0 = f2bf(y0 - bf2f(h0)), l1 = f2bf(y1 - bf2f(h1));
    int ms = m ^ ((q & 7) << 2);
    ((unsigned*)Yhi[q])[ms] = (unsigned)h0 | ((unsigned)h1 << 16);
    ((unsigned*)Ylo[q])[ms] = (unsigned)l0 | ((unsigned)l1 << 16);
  }
  // stage rope'd X tile hi/lo (swizzled)
  for (int pidx = tid; pidx < 1024; pidx += NTHR) {
    int r = pidx >> 5, m = pidx & 31;
    int srow = rowbase + r;
    float2 xv = *(const float2*)(X + (size_t)srow * STRIDE_HD + h * DD + 2 * m);
    float co = cosb[srow * 32 + m], si = sinb[srow * 32 + m];
    float o0 = xv.x * co - xv.y * si;
    float o1 = xv.y * co + xv.x * si;
    unsigned short h0 = f2bf(o0), h1 = f2bf(o1);
    unsigned short l0 = f2bf(o0 - bf2f(h0)), l1 = f2bf(o1 - bf2f(h1));
    int ms = m ^ ((r & 7) << 2);
    ((unsigned*)Xhi[r])[ms] = (unsigned)h0 | ((unsigned)h1 << 16);
    ((unsigned*)Xlo[r])[ms] = (unsigned)l0 | ((unsigned)l1 << 16);
  }
  __syncthreads();

  // B fragments
  bf16x8 Bhi[4], Blo[4];
  {
    const int brow = qt * 32 + arow;
    const int bswz = (brow & 7) << 3;
    #pragma unroll
    for (int ks = 0; ks < 4; ++ks) {
      int kb = (ks * 16 + hi * 8) ^ bswz;
      Bhi[ks] = *(const bf16x8*)&Yhi[brow][kb];
      Blo[ks] = *(const bf16x8*)&Ylo[brow][kb];
    }
  }

  // 12 MFMA (hi*hi + hi*lo + lo*hi)
  f32x16 acc = {0.f,0.f,0.f,0.f,0.f,0.f,0.f,0.f,0.f,0.f,0.f,0.f,0.f,0.f,0.f,0.f};
  {
    const int aswz = (arow & 7) << 3;
    #pragma unroll
    for (int ks = 0; ks < 4; ++ks) {
      int kb = (ks * 16 + hi * 8) ^ aswz;
      bf16x8 Ahi = *(const bf16x8*)&Xhi[arow][kb];
      bf16x8 Alo = *(const bf16x8*)&Xlo[arow][kb];
      acc = __builtin_amdgcn_mfma_f32_32x32x16_bf16(Ahi, Bhi[ks], acc, 0, 0, 0);
      acc = __builtin_amdgcn_mfma_f32_32x32x16_bf16(Ahi, Blo[ks], acc, 0, 0, 0);
      acc = __builtin_amdgcn_mfma_f32_32x32x16_bf16(Alo, Bhi[ks], acc, 0, 0, 0);
    }
  }

  // write C tile
  if (PATH == 0) {
    int col = qt * 32 + arow;
    if (col < 56) {
      #pragma unroll
      for (int rg = 0; rg < 16; ++rg) {
        int P = rowbase + (rg & 3) + 8 * (rg >> 2) + 4 * hi;
        outb[((size_t)h * 2912 + P) * 56 + col] = acc[rg];
      }
    }
  } else {
    int cq = qt * 32 + arow;
    if (cq < 104) {
      int aa = (cq >= 52) ? 1 : 0;
      int jj = cq - aa * 52;
      float* rowp = outb + ((size_t)((h * 2 + aa) * 52 + jj)) * 2912 + rowbase + 4 * hi;
      #pragma unroll
      for (int q4 = 0; q4 < 4; ++q4) {
        f32x4 res = {acc[4 * q4], acc[4 * q4 + 1], acc[4 * q4 + 2], acc[4 * q4 + 3]};
        *(f32x4*)(rowp + 8 * q4) = res;
      }
    }
  }
}

// ===========================================================================
// MAIN: factorized flash attention, 2 j's per block (V regs feed 4 MFMAs).
// ===========================================================================
struct MainPro { float Ls2T[2][2][28][36]; float Rs[2][56][64]; };
union MainShared { MainPro p; float epil[4][16][64]; };

__device__ __forceinline__ bf16x8 make_p8(float Lv, float nm, float4 ra, float4 rb,
                                          int ks, int hi, float& lsum) {
  float p0 = EXP2(fmaf(Lv, ra.x, nm));
  float p1 = EXP2(fmaf(Lv, ra.y, nm));
  float p2 = EXP2(fmaf(Lv, ra.z, nm));
  float p3 = EXP2(fmaf(Lv, ra.w, nm));
  float p4 = EXP2(fmaf(Lv, rb.x, nm));
  float p5 = EXP2(fmaf(Lv, rb.y, nm));
  float p6 = EXP2(fmaf(Lv, rb.z, nm));
  float p7 = EXP2(fmaf(Lv, rb.w, nm));
  if (ks == 3) {
    if (hi == 0) { p4 = 0.f; p5 = 0.f; p6 = 0.f; p7 = 0.f; }
    else { p0 = 0.f; p1 = 0.f; p2 = 0.f; p3 = 0.f;
           p4 = 0.f; p5 = 0.f; p6 = 0.f; p7 = 0.f; }
  }
  lsum += ((p0 + p1) + (p2 + p3)) + ((p4 + p5) + (p6 + p7));
  union { bf16x8 v8; __hip_bfloat162 h2[4]; } pk;
  pk.h2[0] = __float22bfloat162_rn(make_float2(p0, p1));
  pk.h2[1] = __float22bfloat162_rn(make_float2(p2, p3));
  pk.h2[2] = __float22bfloat162_rn(make_float2(p4, p5));
  pk.h2[3] = __float22bfloat162_rn(make_float2(p6, p7));
  return pk.v8;
}

__global__ __launch_bounds__(256, 2)
void k_main(const float* __restrict__ LbufN, const float* __restrict__ Rbuf,
            const unsigned short* __restrict__ vb2, float* __restrict__ outp) {
  const int bid0 = blockIdx.x;
  const int bid = (bid0 & 7) * 78 + (bid0 >> 3);   // 624 = 8*78, XCD-chunked
  const int h = bid / 52;
  const int rem = bid % 52;
  const int a = rem / 26, jp = rem % 26;           // j = 2*jp + jj
  const int tid = threadIdx.x;
  const int lane = tid & 63;
  const int w = tid >> 6;

  __shared__ __align__(16) MainShared ms;
  __shared__ float m2s[2][32], Rmx[2][FB1], Rmn[2][FB1], els[2][4][32];

  const float SC = SCALEF * 1.44269504f;
  for (int idx = tid; idx < 2 * 1568; idx += 256) {
    int jj = idx / 1568, r2 = idx % 1568;
    int i = r2 / 56, fk = r2 % 56;
    int ff = (fk >= 28) ? 1 : 0;
    float v = LbufN[((size_t)h * 2912 + a * 1456 + i * 52 + 2 * jp + jj) * 56 + fk];
    ms.p.Ls2T[jj][ff][fk - ff * 28][i] = v * SC;
  }
  for (int idx = tid; idx < 448; idx += 256) {      // zero pad i=28..31
    int jj = idx / 224, r2 = idx % 224;
    int fk = r2 >> 2;
    int ff = (fk >= 28) ? 1 : 0;
    ms.p.Ls2T[jj][ff][fk - ff * 28][28 + (r2 & 3)] = 0.f;
  }
  for (int idx = tid; idx < 2 * 728; idx += 256) {
    int jj = idx / 728, c4 = idx % 728;
    int fk = c4 / 13, lc = c4 % 13;
    float4 vv = ((const float4*)(Rbuf + ((size_t)(h * 2 + a) * 52 + 2 * jp + jj) * 2912))[c4];
    *(float4*)&ms.p.Rs[jj][fk][lc * 4] = vv;
  }
  __syncthreads();

  if (tid < 112) {                                  // col max/min of R per (jj,fk)
    int jj = tid / 56, fk = tid % 56;
    float mx = -1e30f, mn = 1e30f;
    for (int l = 0; l < 52; ++l) {
      float x = ms.p.Rs[jj][fk][l];
      mx = fmaxf(mx, x); mn = fminf(mn, x);
    }
    Rmx[jj][fk] = mx; Rmn[jj][fk] = mn;
  }
  __syncthreads();

  if (tid < 224) {                                  // exact row max (log2 units)
    int q = tid >> 2, s2 = tid & 3;
    int jj = q / 28, i = q % 28;
    float m = -1e30f;
    #pragma unroll
    for (int n = 0; n < 14; ++n) {
      int fk = s2 * 14 + n;
      int ff = (fk >= 28) ? 1 : 0;
      float Lv = ms.p.Ls2T[jj][ff][fk - ff * 28][i];
      m = fmaxf(m, fmaxf(Lv * Rmx[jj][fk], Lv * Rmn[jj][fk]));
    }
    m = fmaxf(m, __shfl_xor(m, 1));
    m = fmaxf(m, __shfl_xor(m, 2));
    if (s2 == 0) m2s[jj][i] = m;
  }
  if (tid >= 248) { int r = tid - 248; m2s[r >> 2][28 + (r & 3)] = 0.f; }
  __syncthreads();

  const int row = lane & 31;
  const int hi = lane >> 5;
  const float nm0 = -m2s[0][row], nm1 = -m2s[1][row];
  const bf16x8* vw = (const bf16x8*)vb2 + (size_t)h * 28672 + hi * 64 + row;

  f32x16 a00 = {0.f,0.f,0.f,0.f,0.f,0.f,0.f,0.f,0.f,0.f,0.f,0.f,0.f,0.f,0.f,0.f};
  f32x16 a01 = a00, a10 = a00, a11 = a00;
  float ls0 = 0.f, ls1 = 0.f;

  for (int t = 0; t < 14; ++t) {
    const int fk = w * 14 + t;
    const int ff = (fk >= 28) ? 1 : 0, kk = fk - ff * 28;
    const float Lv0 = ms.p.Ls2T[0][ff][kk][row];
    const float Lv1 = ms.p.Ls2T[1][ff][kk][row];
    const bf16x8* vp = vw + (size_t)fk * 512;
    #pragma unroll
    for (int ks = 0; ks < 4; ++ks) {
      const int k0 = ks * 16 + hi * 8;
      float4 ra0 = *(const float4*)&ms.p.Rs[0][fk][k0];
      float4 rb0 = *(const float4*)&ms.p.Rs[0][fk][k0 + 4];
      float4 ra1 = *(const float4*)&ms.p.Rs[1][fk][k0];
      float4 rb1 = *(const float4*)&ms.p.Rs[1][fk][k0 + 4];
      bf16x8 pk0 = make_p8(Lv0, nm0, ra0, rb0, ks, hi, ls0);
      bf16x8 pk1 = make_p8(Lv1, nm1, ra1, rb1, ks, hi, ls1);
      bf16x8 b0 = vp[ks * 128];
      bf16x8 b1 = vp[ks * 128 + 32];
      a00 = __builtin_amdgcn_mfma_f32_32x32x16_bf16(pk0, b0, a00, 0, 0, 0);
      a01 = __builtin_amdgcn_mfma_f32_32x32x16_bf16(pk0, b1, a01, 0, 0, 0);
      a10 = __builtin_amdgcn_mfma_f32_32x32x16_bf16(pk1, b0, a10, 0, 0, 0);
      a11 = __builtin_amdgcn_mfma_f32_32x32x16_bf16(pk1, b1, a11, 0, 0, 0);
    }
  }

  ls0 += __shfl_xor(ls0, 32);
  ls1 += __shfl_xor(ls1, 32);
  if (lane < 32) { els[0][w][lane] = ls0; els[1][w][lane] = ls1; }
  __syncthreads();                                   // Rs/Ls2T reads done; els visible

#define EPIL_ROUND(ACC, JJ, HALF, FIRST)                                        \
  {                                                                             \
    if (!(FIRST)) __syncthreads();                                              \
    _Pragma("unroll")                                                           \
    for (int r = 0; r < 16; ++r) ms.epil[w][r][lane] = ACC[r];                  \
    __syncthreads();                                                            \
    _Pragma("unroll")                                                           \
    for (int q = 0; q < 4; ++q) {                                               \
      int r = w + q * 4;                                                        \
      int elane = tid & 63;                                                     \
      float val = ms.epil[0][r][elane] + ms.epil[1][r][elane]                   \
                + ms.epil[2][r][elane] + ms.epil[3][r][elane];                  \
      int irow = (r & 3) + 8 * (r >> 2) + 4 * (elane >> 5);                     \
      if (irow < NB1) {                                                         \
        float li = 1.0f / (els[JJ][0][irow] + els[JJ][1][irow]                  \
                         + els[JJ][2][irow] + els[JJ][3][irow]);                \
        int srow = a * 1456 + irow * 52 + 2 * jp + (JJ);                        \
        outp[(size_t)srow * STRIDE_HD + h * DD + (HALF) * 32 + (elane & 31)]    \
            = val * li;                                                         \
      }                                                                         \
    }                                                                           \
  }

  EPIL_ROUND(a00, 0, 0, 1)
  EPIL_ROUND(a01, 0, 1, 0)
  EPIL_ROUND(a10, 1, 0, 0)
  EPIL_ROUND(a11, 1, 1, 0)
#undef EPIL_ROUND
}

// ---------------------------------------------------------------------------
extern "C" void kernel_launch(void* const* d_in, const int* in_sizes, int n_in,
                              void* d_out, int out_size, void* d_ws, size_t ws_size,
                              hipStream_t stream) {
  (void)in_sizes; (void)n_in; (void)out_size; (void)ws_size;
  const float* lq   = (const float*)d_in[0];
  const float* lk   = (const float*)d_in[1];
  const float* rq   = (const float*)d_in[2];
  const float* rk   = (const float*)d_in[3];
  const float* v    = (const float*)d_in[4];
  const float* cosb = (const float*)d_in[5];
  const float* sinb = (const float*)d_in[6];
  const float* W_lkq = (const float*)d_in[7];  const float* b_lkq = (const float*)d_in[8];
  const float* W_lkk = (const float*)d_in[9];  const float* b_lkk = (const float*)d_in[10];
  const float* W_lkv = (const float*)d_in[11]; const float* b_lkv = (const float*)d_in[12];
  const float* W_rqq = (const float*)d_in[13]; const float* b_rqq = (const float*)d_in[14];
  const float* W_rqk = (const float*)d_in[15]; const float* b_rqk = (const float*)d_in[16];
  const float* W_rqv = (const float*)d_in[17]; const float* b_rqv = (const float*)d_in[18];

  float* ws = (float*)d_ws;
  float* lk_out = ws;                                   // 43008
  float* rq_out = ws + 43008;                           // 79872
  float* LbufN  = ws + 122880;                          // 1956864 (12*2912*56)
  float* Rbuf   = ws + 2079744;                         // 3634176
  unsigned short* vb2 = (unsigned short*)(ws + 5713920);// 2752512 shorts
  float* ql     = ws + 7090176;                         // 43008
  float* qr     = ws + 7133184;                         // 79872
  // Klg/Krg alias the LbufN/Rbuf space (dead before k_midg writes them)
  float* Klg = LbufN;                                   // 2236416
  float* Krg = LbufN + 2236416;                         // 2236416 (ends < Rbuf end)

  k_proj<<<1140, 256, 0, stream>>>(lk, rq, cosb, sinb,
      W_lkk, b_lkk, W_rqk, b_rqk, W_lkq, b_lkq, W_rqq, b_rqq,
      Klg, Krg, ql, qr);
  k_sv<<<2592, 256, 0, stream>>>(lk, rq, v, cosb, sinb, Klg, Krg, ql, qr,
      W_lkv, b_lkv, W_rqv, b_rqv, lk_out, rq_out, vb2);
  k_midg<64, 56, 128, 0><<<1092, 128, 0, stream>>>(lq, lk_out, cosb, sinb, LbufN);
  k_midg<128, 104, 256, 1><<<1092, 256, 0, stream>>>(rk, rq_out, cosb, sinb, Rbuf);
  k_main<<<624, 256, 0, stream>>>(LbufN, Rbuf, vb2, (float*)d_out);
}

// Round 10
// 99.309 us; speedup vs baseline: 1.3274x; 1.1427x over previous
//
#include <hip/hip_runtime.h>
#include <hip/hip_bf16.h>

#define HH 12
#define DD 64
#define NB1 28
#define NB2 52
#define NF 2
#define FB1 56           // NF*NB1
#define FB2 104          // NF*NB2
#define STRIDE_HD 768    // HH*DD
#define SCALEF 0.125f

typedef float f32x4 __attribute__((ext_vector_type(4)));
typedef float f32x16 __attribute__((ext_vector_type(16)));
typedef short bf16x8 __attribute__((ext_vector_type(8)));

#if __has_builtin(__builtin_amdgcn_exp2f)
#define EXP2(x) __builtin_amdgcn_exp2f(x)
#else
#define EXP2(x) __expf((x) * 0.6931471805599453f)
#endif

__device__ __forceinline__ unsigned short f2bf(float x) {
  union { float f; unsigned u; } c; c.f = x;
  unsigned r = c.u + 0x7fffu + ((c.u >> 16) & 1u);
  return (unsigned short)(r >> 16);
}
__device__ __forceinline__ float bf2f(unsigned short u) {
  union { unsigned u32v; float f; } c; c.u32v = ((unsigned)u) << 16; return c.f;
}

// ===========================================================================
// k_proj: 64-row x 64-out projection tiles + rope, outputs key-grouped.
// ===========================================================================
__global__ __launch_bounds__(256, 4)
void k_proj(const float* __restrict__ lk, const float* __restrict__ rq,
            const float* __restrict__ cosb, const float* __restrict__ sinb,
            const float* __restrict__ W_lkk, const float* __restrict__ b_lkk,
            const float* __restrict__ W_rqk, const float* __restrict__ b_rqk,
            const float* __restrict__ W_lkq, const float* __restrict__ b_lkq,
            const float* __restrict__ W_rqq, const float* __restrict__ b_rqq,
            float* __restrict__ Klg, float* __restrict__ Krg,
            float* __restrict__ ql, float* __restrict__ qr) {
  __shared__ __align__(16) float Wt[64][68];   // [d][e]
  __shared__ __align__(16) float xs[64][68];   // [r][d]
  __shared__ int srows[64];
  __shared__ int obase[64];

  const int tid = threadIdx.x;
  int bx = blockIdx.x;
  int path, h, c;
  if (bx < 552)       { path = 0; h = bx / 46; c = bx % 46; }
  else if (bx < 1104) { path = 1; bx -= 552;  h = bx / 46; c = bx % 46; }
  else if (bx < 1116) { path = 2; h = bx - 1104; c = 0; }
  else                { path = 3; bx -= 1116; h = bx >> 1; c = bx & 1; }

  const float* X  = (path == 1 || path == 3) ? rq : lk;
  const float* W  = (path == 0) ? W_lkk : (path == 1) ? W_rqk : (path == 2) ? W_lkq : W_rqq;
  const float* bb = (path == 0) ? b_lkk : (path == 1) ? b_rqk : (path == 2) ? b_lkq : b_rqq;
  float* out      = (path == 0) ? Klg : (path == 1) ? Krg : (path == 2) ? ql : qr;
  const int nrows = (path == 0 || path == 1) ? ((c == 45) ? 32 : 64)
                   : (path == 2) ? 56 : ((c == 1) ? 40 : 64);

  for (int idx = tid; idx < 4096; idx += 256)
    Wt[idx & 63][idx >> 6] = W[(size_t)h * 4096 + idx];
  if (tid < 64) {
    int rr = tid, s = 0, ob = 0;
    if (rr < nrows) {
      if (path == 0) {
        s = c * 64 + rr;
        int f = s / 1456, rem = s % 1456, b1 = rem / 52, b2 = rem % 52;
        ob = ((h * 56 + f * 28 + b1) * 52 + b2) * 64;
      } else if (path == 1) {
        s = c * 64 + rr;
        int f = s / 1456, rem = s % 1456, b1 = rem / 52, jj = rem % 52;
        ob = ((h * 104 + f * 52 + jj) * 28 + b1) * 64;
      } else if (path == 2) {
        int q = rr;
        s = (q / 28) * 1456 + (q % 28) * 52;
        ob = (h * 56 + q) * 64;
      } else {
        int q = c * 64 + rr;
        s = (q / 52) * 1456 + (q % 52);
        ob = (h * 104 + q) * 64;
      }
    }
    srows[rr] = s; obase[rr] = ob;
  }
  __syncthreads();
  for (int idx = tid; idx < 4096; idx += 256) {
    int r = idx >> 6, d = idx & 63;
    xs[r][d] = X[(size_t)srows[r] * STRIDE_HD + h * DD + d];
  }
  __syncthreads();

  const int it = tid >> 4, kt = tid & 15;
  f32x4 acc0 = {0,0,0,0}, acc1 = {0,0,0,0}, acc2 = {0,0,0,0}, acc3 = {0,0,0,0};
  #pragma unroll 4
  for (int d4 = 0; d4 < 16; ++d4) {
    f32x4 x0 = *(const f32x4*)&xs[4 * it][4 * d4];
    f32x4 x1 = *(const f32x4*)&xs[4 * it + 1][4 * d4];
    f32x4 x2 = *(const f32x4*)&xs[4 * it + 2][4 * d4];
    f32x4 x3 = *(const f32x4*)&xs[4 * it + 3][4 * d4];
    #pragma unroll
    for (int dd = 0; dd < 4; ++dd) {
      f32x4 wv = *(const f32x4*)&Wt[4 * d4 + dd][4 * kt];
      acc0 += x0[dd] * wv;
      acc1 += x1[dd] * wv;
      acc2 += x2[dd] * wv;
      acc3 += x3[dd] * wv;
    }
  }

  f32x4 bv;
  bv[0] = bb[h * 64 + 4 * kt];     bv[1] = bb[h * 64 + 4 * kt + 1];
  bv[2] = bb[h * 64 + 4 * kt + 2]; bv[3] = bb[h * 64 + 4 * kt + 3];
  #pragma unroll
  for (int rr = 0; rr < 4; ++rr) {
    int row = 4 * it + rr;
    if (row < nrows) {
      f32x4 o = (rr == 0) ? acc0 : (rr == 1) ? acc1 : (rr == 2) ? acc2 : acc3;
      o += bv;
      int s = srows[row];
      float c0 = cosb[s * 32 + 2 * kt],     s0 = sinb[s * 32 + 2 * kt];
      float c1 = cosb[s * 32 + 2 * kt + 1], s1 = sinb[s * 32 + 2 * kt + 1];
      f32x4 res;
      res[0] = o[0] * c0 - o[1] * s0;
      res[1] = o[1] * c0 + o[0] * s0;
      res[2] = o[2] * c1 - o[3] * s1;
      res[3] = o[3] * c1 + o[2] * s1;
      *(f32x4*)(out + obase[row] + 4 * kt) = res;
    }
  }
}

// ===========================================================================
// k_sv: per-(n,h) tiny SDPA (wide phases) for both paths + V bf16 re-layout
// ===========================================================================
struct SvShared {
  union {
    struct { float qv[64]; float sc[64]; float ps[64]; float ys[64]; float oe[64]; } s;
    float tile[52][68];
  } u;
};

template<int NK, int NG, int GD, int GMUL, int KSTR>
__device__ void sdpa_path(int n, int h, const float* __restrict__ X,
                          const float* __restrict__ Kg, const float* __restrict__ qb,
                          const float* __restrict__ cosb, const float* __restrict__ sinb,
                          const float* __restrict__ Wv, const float* __restrict__ bvv,
                          float* __restrict__ outb, SvShared& sm) {
  const int t = threadIdx.x;
  const int f = n / GD, g = n % GD;
  const int s_base = f * (NB1 * NB2) + g * GMUL;

  if (t < 64) sm.u.s.qv[t] = qb[(size_t)(h * NG + n) * 64 + t];
  __syncthreads();

  if (t < NK * 4) {
    int r = t >> 2, part = t & 3;
    const float4* kr = (const float4*)(Kg + ((size_t)(h * NG + n) * NK + r) * 64 + part * 16);
    const float4* q4 = (const float4*)(sm.u.s.qv + part * 16);
    float p = 0.f;
    #pragma unroll
    for (int i = 0; i < 4; ++i) {
      float4 kv = kr[i], qv4 = q4[i];
      p += kv.x * qv4.x + kv.y * qv4.y + kv.z * qv4.z + kv.w * qv4.w;
    }
    p += __shfl_xor(p, 1); p += __shfl_xor(p, 2);
    if (part == 0) sm.u.s.sc[r] = p * SCALEF;
  }
  __syncthreads();

  if (t < 64) {
    float v = (t < NK) ? sm.u.s.sc[t] : -1e30f;
    float mx = v;
    for (int o = 32; o; o >>= 1) mx = fmaxf(mx, __shfl_xor(mx, o));
    float e = (t < NK) ? __expf(v - mx) : 0.f;
    float sum = e;
    for (int o = 32; o; o >>= 1) sum += __shfl_xor(sum, o);
    sm.u.s.ps[t] = (t < NK) ? e / sum : 0.f;
  }
  __syncthreads();

  {
    int d = t >> 2, g4 = t & 3;
    constexpr int RPG = NK / 4;
    float yp = 0.f;
    #pragma unroll 4
    for (int rr = 0; rr < RPG; ++rr) {
      int r = g4 * RPG + rr;
      yp += sm.u.s.ps[r] * X[(size_t)(s_base + r * KSTR) * STRIDE_HD + h * DD + d];
    }
    yp += __shfl_xor(yp, 1); yp += __shfl_xor(yp, 2);
    if (g4 == 0) sm.u.s.ys[d] = yp;
  }
  __syncthreads();

  {
    int e = t >> 2, part = t & 3;
    const float4* wr = (const float4*)(Wv + (size_t)h * 4096 + e * 64 + part * 16);
    const float4* y4 = (const float4*)(sm.u.s.ys + part * 16);
    float p = 0.f;
    #pragma unroll
    for (int i = 0; i < 4; ++i) {
      float4 wv = wr[i], yv = y4[i];
      p += wv.x * yv.x + wv.y * yv.y + wv.z * yv.z + wv.w * yv.w;
    }
    p += __shfl_xor(p, 1); p += __shfl_xor(p, 2);
    if (part == 0) sm.u.s.oe[e] = p + bvv[h * 64 + e];
  }
  __syncthreads();

  if (t < 32) {
    float co = cosb[s_base * 32 + t], si = sinb[s_base * 32 + t];
    float o0 = sm.u.s.oe[2 * t], o1 = sm.u.s.oe[2 * t + 1];
    outb[(size_t)n * STRIDE_HD + h * DD + 2 * t]     = o0 * co - o1 * si;
    outb[(size_t)n * STRIDE_HD + h * DD + 2 * t + 1] = o1 * co + o0 * si;
  }
}

// v (S,H,D) f32 -> vb2[h][fk][l8][d][li] bf16 (l = l8*8+li, l>=52 zero)
__device__ void vb_path(int fk, int h, const float* __restrict__ v,
                        unsigned short* __restrict__ vb2, SvShared& sm) {
  const int tid = threadIdx.x;
  for (int idx = tid; idx < NB2 * DD; idx += 256) {
    int l = idx >> 6, d = idx & 63;
    sm.u.tile[l][d] = v[(size_t)(fk * NB2 + l) * STRIDE_HD + h * DD + d];
  }
  __syncthreads();
  for (int idx = tid; idx < 512; idx += 256) {
    int l8 = idx >> 6, d = idx & 63;
    unsigned short tmp[8];
    #pragma unroll
    for (int li = 0; li < 8; ++li) {
      int l = l8 * 8 + li;
      tmp[li] = (l < NB2) ? f2bf(sm.u.tile[l][d]) : (unsigned short)0;
    }
    bf16x8* dst = (bf16x8*)(vb2 + (((size_t)(h * FB1 + fk) * 8 + l8) * 64 + d) * 8);
    *dst = *(bf16x8*)tmp;
  }
}

__global__ __launch_bounds__(256)
void k_sv(const float* __restrict__ lk, const float* __restrict__ rq,
          const float* __restrict__ v,
          const float* __restrict__ cosb, const float* __restrict__ sinb,
          const float* __restrict__ Klg, const float* __restrict__ Krg,
          const float* __restrict__ ql, const float* __restrict__ qr,
          const float* __restrict__ W_lkv, const float* __restrict__ b_lkv,
          const float* __restrict__ W_rqv, const float* __restrict__ b_rqv,
          float* __restrict__ lk_out, float* __restrict__ rq_out,
          unsigned short* __restrict__ vb2) {
  __shared__ SvShared sm;
  const int bx = blockIdx.x;
  if (bx < 672) {
    sdpa_path<52, 56, 28, 52, 1>(bx % 56, bx / 56, lk, Klg, ql, cosb, sinb,
                                 W_lkv, b_lkv, lk_out, sm);
  } else if (bx < 1920) {
    int id = bx - 672;
    sdpa_path<28, 104, 52, 1, 52>(id % 104, id / 104, rq, Krg, qr, cosb, sinb,
                                  W_rqv, b_rqv, rq_out, sm);
  } else {
    int id = bx - 1920;
    vb_path(id % 56, id / 56, v, vb2, sm);
  }
}

// ===========================================================================
// MID (MFMA, hi/lo bf16 split), single merged launch:
//  bx < 552:  L  (h, 64-row X-tile of lq; Y=lk_out 56; waves = 2 xt x 2 qt)
//  bx >= 552: R  (h, 32-row X-tile of rk; Y=rq_out 104; waves = 4 qt)
// L out: LbufN[h][P][col]; R out: Rbuf[(h,aa,jj)][P].
// ===========================================================================
struct MgL { unsigned short Yhi[64][64];  unsigned short Ylo[64][64];
             unsigned short Xhi[64][64];  unsigned short Xlo[64][64]; };
struct MgR { unsigned short Yhi[128][64]; unsigned short Ylo[128][64];
             unsigned short Xhi[32][64];  unsigned short Xlo[32][64]; };
union MgShared { MgL L; MgR R; };

__global__ __launch_bounds__(256, 4)
void k_midg(const float* __restrict__ lq, const float* __restrict__ rk,
            const float* __restrict__ lk_out, const float* __restrict__ rq_out,
            const float* __restrict__ cosb, const float* __restrict__ sinb,
            float* __restrict__ LbufN, float* __restrict__ Rbuf) {
  __shared__ __align__(16) MgShared sh;
  const int tid = threadIdx.x;
  const int lane = tid & 63, w = tid >> 6;
  const int hi = lane >> 5, arow = lane & 31;
  int bx = blockIdx.x;

  if (bx < 552) {
    const int h = bx / 46, pt = bx % 46;
    const int rowbase = pt * 64;
    for (int idx = tid; idx < 2048; idx += 256) {           // Y (56 valid)
      int q = idx >> 5, m = idx & 31;
      float y0 = 0.f, y1 = 0.f;
      if (q < 56) {
        float2 yv = *(const float2*)(lk_out + (size_t)q * STRIDE_HD + h * DD + 2 * m);
        y0 = yv.x; y1 = yv.y;
      }
      unsigned short h0 = f2bf(y0), h1 = f2bf(y1);
      unsigned short l0 = f2bf(y0 - bf2f(h0)), l1 = f2bf(y1 - bf2f(h1));
      int ms2 = m ^ ((q & 7) << 2);
      ((unsigned*)sh.L.Yhi[q])[ms2] = (unsigned)h0 | ((unsigned)h1 << 16);
      ((unsigned*)sh.L.Ylo[q])[ms2] = (unsigned)l0 | ((unsigned)l1 << 16);
    }
    for (int idx = tid; idx < 2048; idx += 256) {           // X + rope
      int r = idx >> 5, m = idx & 31;
      int srow = rowbase + r;
      float o0 = 0.f, o1 = 0.f;
      if (srow < 2912) {
        float2 xv = *(const float2*)(lq + (size_t)srow * STRIDE_HD + h * DD + 2 * m);
        float co = cosb[srow * 32 + m], si = sinb[srow * 32 + m];
        o0 = xv.x * co - xv.y * si;
        o1 = xv.y * co + xv.x * si;
      }
      unsigned short h0 = f2bf(o0), h1 = f2bf(o1);
      unsigned short l0 = f2bf(o0 - bf2f(h0)), l1 = f2bf(o1 - bf2f(h1));
      int ms2 = m ^ ((r & 7) << 2);
      ((unsigned*)sh.L.Xhi[r])[ms2] = (unsigned)h0 | ((unsigned)h1 << 16);
      ((unsigned*)sh.L.Xlo[r])[ms2] = (unsigned)l0 | ((unsigned)l1 << 16);
    }
    __syncthreads();

    const int xt = w >> 1, qt = w & 1;
    const int brow = qt * 32 + arow;
    const int bswz = (brow & 7) << 3;
    const int xrow = xt * 32 + arow;
    const int aswz = (xrow & 7) << 3;
    f32x16 acc = {0.f,0.f,0.f,0.f,0.f,0.f,0.f,0.f,0.f,0.f,0.f,0.f,0.f,0.f,0.f,0.f};
    #pragma unroll
    for (int ks = 0; ks < 4; ++ks) {
      int kbB = (ks * 16 + hi * 8) ^ bswz;
      int kbA = (ks * 16 + hi * 8) ^ aswz;
      bf16x8 Bhi = *(const bf16x8*)&sh.L.Yhi[brow][kbB];
      bf16x8 Blo = *(const bf16x8*)&sh.L.Ylo[brow][kbB];
      bf16x8 Ahi = *(const bf16x8*)&sh.L.Xhi[xrow][kbA];
      bf16x8 Alo = *(const bf16x8*)&sh.L.Xlo[xrow][kbA];
      acc = __builtin_amdgcn_mfma_f32_32x32x16_bf16(Ahi, Bhi, acc, 0, 0, 0);
      acc = __builtin_amdgcn_mfma_f32_32x32x16_bf16(Ahi, Blo, acc, 0, 0, 0);
      acc = __builtin_amdgcn_mfma_f32_32x32x16_bf16(Alo, Bhi, acc, 0, 0, 0);
    }
    int col = qt * 32 + arow;
    if (col < 56) {
      #pragma unroll
      for (int rg = 0; rg < 16; ++rg) {
        int P = rowbase + xt * 32 + (rg & 3) + 8 * (rg >> 2) + 4 * hi;
        if (P < 2912)
          LbufN[((size_t)h * 2912 + P) * 56 + col] = acc[rg];
      }
    }
  } else {
    bx -= 552;
    const int h = bx / 91, pt = bx % 91;
    const int rowbase = pt * 32;
    for (int idx = tid; idx < 4096; idx += 256) {           // Y (104 valid)
      int q = idx >> 5, m = idx & 31;
      float y0 = 0.f, y1 = 0.f;
      if (q < 104) {
        float2 yv = *(const float2*)(rq_out + (size_t)q * STRIDE_HD + h * DD + 2 * m);
        y0 = yv.x; y1 = yv.y;
      }
      unsigned short h0 = f2bf(y0), h1 = f2bf(y1);
      unsigned short l0 = f2bf(y0 - bf2f(h0)), l1 = f2bf(y1 - bf2f(h1));
      int ms2 = m ^ ((q & 7) << 2);
      ((unsigned*)sh.R.Yhi[q])[ms2] = (unsigned)h0 | ((unsigned)h1 << 16);
      ((unsigned*)sh.R.Ylo[q])[ms2] = (unsigned)l0 | ((unsigned)l1 << 16);
    }
    for (int idx = tid; idx < 1024; idx += 256) {           // X + rope
      int r = idx >> 5, m = idx & 31;
      int srow = rowbase + r;
      float2 xv = *(const float2*)(rk + (size_t)srow * STRIDE_HD + h * DD + 2 * m);
      float co = cosb[srow * 32 + m], si = sinb[srow * 32 + m];
      float o0 = xv.x * co - xv.y * si;
      float o1 = xv.y * co + xv.x * si;
      unsigned short h0 = f2bf(o0), h1 = f2bf(o1);
      unsigned short l0 = f2bf(o0 - bf2f(h0)), l1 = f2bf(o1 - bf2f(h1));
      int ms2 = m ^ ((r & 7) << 2);
      ((unsigned*)sh.R.Xhi[r])[ms2] = (unsigned)h0 | ((unsigned)h1 << 16);
      ((unsigned*)sh.R.Xlo[r])[ms2] = (unsigned)l0 | ((unsigned)l1 << 16);
    }
    __syncthreads();

    const int brow = w * 32 + arow;
    const int bswz = (brow & 7) << 3;
    const int aswz = (arow & 7) << 3;
    f32x16 acc = {0.f,0.f,0.f,0.f,0.f,0.f,0.f,0.f,0.f,0.f,0.f,0.f,0.f,0.f,0.f,0.f};
    #pragma unroll
    for (int ks = 0; ks < 4; ++ks) {
      int kbB = (ks * 16 + hi * 8) ^ bswz;
      int kbA = (ks * 16 + hi * 8) ^ aswz;
      bf16x8 Bhi = *(const bf16x8*)&sh.R.Yhi[brow][kbB];
      bf16x8 Blo = *(const bf16x8*)&sh.R.Ylo[brow][kbB];
      bf16x8 Ahi = *(const bf16x8*)&sh.R.Xhi[arow][kbA];
      bf16x8 Alo = *(const bf16x8*)&sh.R.Xlo[arow][kbA];
      acc = __builtin_amdgcn_mfma_f32_32x32x16_bf16(Ahi, Bhi, acc, 0, 0, 0);
      acc = __builtin_amdgcn_mfma_f32_32x32x16_bf16(Ahi, Blo, acc, 0, 0, 0);
      acc = __builtin_amdgcn_mfma_f32_32x32x16_bf16(Alo, Bhi, acc, 0, 0, 0);
    }
    int cq = w * 32 + arow;
    if (cq < 104) {
      int aa = (cq >= 52) ? 1 : 0;
      int jj = cq - aa * 52;
      float* rowp = Rbuf + ((size_t)((h * 2 + aa) * 52 + jj)) * 2912 + rowbase + 4 * hi;
      #pragma unroll
      for (int q4 = 0; q4 < 4; ++q4) {
        f32x4 res = {acc[4 * q4], acc[4 * q4 + 1], acc[4 * q4 + 2], acc[4 * q4 + 3]};
        *(f32x4*)(rowp + 8 * q4) = res;
      }
    }
  }
}

// ===========================================================================
// MAIN: factorized flash attention, 1 j per block, L in registers, slim LDS.
// ===========================================================================
__device__ __forceinline__ bf16x8 make_p8(float Lv, float nm, float4 ra, float4 rb,
                                          int ks, int hi, float& lsum) {
  float p0 = EXP2(fmaf(Lv, ra.x, nm));
  float p1 = EXP2(fmaf(Lv, ra.y, nm));
  float p2 = EXP2(fmaf(Lv, ra.z, nm));
  float p3 = EXP2(fmaf(Lv, ra.w, nm));
  float p4 = EXP2(fmaf(Lv, rb.x, nm));
  float p5 = EXP2(fmaf(Lv, rb.y, nm));
  float p6 = EXP2(fmaf(Lv, rb.z, nm));
  float p7 = EXP2(fmaf(Lv, rb.w, nm));
  if (ks == 3) {
    if (hi == 0) { p4 = 0.f; p5 = 0.f; p6 = 0.f; p7 = 0.f; }
    else { p0 = 0.f; p1 = 0.f; p2 = 0.f; p3 = 0.f;
           p4 = 0.f; p5 = 0.f; p6 = 0.f; p7 = 0.f; }
  }
  lsum += ((p0 + p1) + (p2 + p3)) + ((p4 + p5) + (p6 + p7));
  union { bf16x8 v8; __hip_bfloat162 h2[4]; } pk;
  pk.h2[0] = __float22bfloat162_rn(make_float2(p0, p1));
  pk.h2[1] = __float22bfloat162_rn(make_float2(p2, p3));
  pk.h2[2] = __float22bfloat162_rn(make_float2(p4, p5));
  pk.h2[3] = __float22bfloat162_rn(make_float2(p6, p7));
  return pk.v8;
}

__global__ __launch_bounds__(256, 4)
void k_main(const float* __restrict__ LbufN, const float* __restrict__ Rbuf,
            const unsigned short* __restrict__ vb2, float* __restrict__ outp) {
  const int bid0 = blockIdx.x;
  const int bid = (bid0 & 7) * 156 + (bid0 >> 3);   // 1248 = 8*156, XCD-chunked
  const int h = bid / (NF * NB2);
  const int rem = bid % (NF * NB2);
  const int a = rem / NB2, j = rem % NB2;
  const int tid = threadIdx.x;
  const int lane = tid & 63;
  const int w = tid >> 6;
  const int row = lane & 31;
  const int hi = lane >> 5;

  __shared__ __align__(16) union { float Rs[56][64]; float epil[4][16][64]; } ms;
  __shared__ float Rmx[FB1], Rmn[FB1], pmax[4][32], els[4][32];

  // Rs staging (52 valid l per fk; 52..63 garbage, masked at ks==3)
  const float* Rrow = Rbuf + ((size_t)(h * 2 + a) * 52 + j) * 2912;
  for (int idx = tid; idx < 728; idx += 256) {
    int fk = idx / 13, lc = idx % 13;
    float4 vv = ((const float4*)Rrow)[idx];
    *(float4*)&ms.Rs[fk][lc * 4] = vv;
  }
  __syncthreads();

  if (tid < 224) {                                  // col max/min of R
    int fk = tid >> 2, part = tid & 3;
    float mx = -1e30f, mn = 1e30f;
    for (int l = part * 13; l < part * 13 + 13; ++l) {
      float x = ms.Rs[fk][l];
      mx = fmaxf(mx, x); mn = fminf(mn, x);
    }
    mx = fmaxf(mx, __shfl_xor(mx, 1)); mn = fminf(mn, __shfl_xor(mn, 1));
    mx = fmaxf(mx, __shfl_xor(mx, 2)); mn = fminf(mn, __shfl_xor(mn, 2));
    if (part == 0) { Rmx[fk] = mx; Rmn[fk] = mn; }
  }

  // L values for this lane's row, this wave's 14 fk's (registers)
  const float SC = SCALEF * 1.44269504f;
  float Lv[14];
  {
    const float* Lrow = LbufN + ((size_t)h * 2912 + a * 1456 + row * 52 + j) * 56 + w * 14;
    #pragma unroll
    for (int t = 0; t < 14; ++t)
      Lv[t] = (row < NB1) ? Lrow[t] * SC : 0.f;
  }
  __syncthreads();                                  // Rmx/Rmn ready

  // exact row max: per-lane partial over 14 fk, combine across 4 waves
  {
    float pm = -1e30f;
    #pragma unroll
    for (int t = 0; t < 14; ++t) {
      int fk = w * 14 + t;
      pm = fmaxf(pm, fmaxf(Lv[t] * Rmx[fk], Lv[t] * Rmn[fk]));
    }
    if (hi == 0) pmax[w][row] = pm;
  }
  __syncthreads();
  const float m2 = fmaxf(fmaxf(pmax[0][row], pmax[1][row]),
                         fmaxf(pmax[2][row], pmax[3][row]));
  const float nm = -m2;

  const bf16x8* vw = (const bf16x8*)vb2 + (size_t)h * 28672 + hi * 64 + row;

  f32x16 acc0 = {0.f,0.f,0.f,0.f,0.f,0.f,0.f,0.f,0.f,0.f,0.f,0.f,0.f,0.f,0.f,0.f};
  f32x16 acc1 = acc0;
  float lsum = 0.f;

  #pragma unroll
  for (int t = 0; t < 14; ++t) {
    const int fk = w * 14 + t;
    const bf16x8* vp = vw + (size_t)fk * 512;
    #pragma unroll
    for (int ks = 0; ks < 4; ++ks) {
      const int k0 = ks * 16 + hi * 8;
      float4 ra = *(const float4*)&ms.Rs[fk][k0];
      float4 rb = *(const float4*)&ms.Rs[fk][k0 + 4];
      bf16x8 pk = make_p8(Lv[t], nm, ra, rb, ks, hi, lsum);
      bf16x8 b0 = vp[ks * 128];
      bf16x8 b1 = vp[ks * 128 + 32];
      acc0 = __builtin_amdgcn_mfma_f32_32x32x16_bf16(pk, b0, acc0, 0, 0, 0);
      acc1 = __builtin_amdgcn_mfma_f32_32x32x16_bf16(pk, b1, acc1, 0, 0, 0);
    }
  }

  lsum += __shfl_xor(lsum, 32);
  if (lane < 32) els[w][lane] = lsum;
  __syncthreads();                                  // Rs reads done; els visible

  // epilogue: 2 rounds (d-halves) of 4-segment reduction through LDS
  #pragma unroll
  for (int half = 0; half < 2; ++half) {
    if (half) __syncthreads();
    #pragma unroll
    for (int r = 0; r < 16; ++r)
      ms.epil[w][r][lane] = half ? acc1[r] : acc0[r];
    __syncthreads();
    #pragma unroll
    for (int q = 0; q < 4; ++q) {
      int r = w + q * 4;
      int elane = tid & 63;
      float val = ms.epil[0][r][elane] + ms.epil[1][r][elane]
                + ms.epil[2][r][elane] + ms.epil[3][r][elane];
      int irow = (r & 3) + 8 * (r >> 2) + 4 * (elane >> 5);
      if (irow < NB1) {
        float li = 1.0f / (els[0][irow] + els[1][irow] + els[2][irow] + els[3][irow]);
        int srow = a * (NB1 * NB2) + irow * NB2 + j;
        int d = half * 32 + (elane & 31);
        outp[(size_t)srow * STRIDE_HD + h * DD + d] = val * li;
      }
    }
  }
}

// ---------------------------------------------------------------------------
extern "C" void kernel_launch(void* const* d_in, const int* in_sizes, int n_in,
                              void* d_out, int out_size, void* d_ws, size_t ws_size,
                              hipStream_t stream) {
  (void)in_sizes; (void)n_in; (void)out_size; (void)ws_size;
  const float* lq   = (const float*)d_in[0];
  const float* lk   = (const float*)d_in[1];
  const float* rq   = (const float*)d_in[2];
  const float* rk   = (const float*)d_in[3];
  const float* v    = (const float*)d_in[4];
  const float* cosb = (const float*)d_in[5];
  const float* sinb = (const float*)d_in[6];
  const float* W_lkq = (const float*)d_in[7];  const float* b_lkq = (const float*)d_in[8];
  const float* W_lkk = (const float*)d_in[9];  const float* b_lkk = (const float*)d_in[10];
  const float* W_lkv = (const float*)d_in[11]; const float* b_lkv = (const float*)d_in[12];
  const float* W_rqq = (const float*)d_in[13]; const float* b_rqq = (const float*)d_in[14];
  const float* W_rqk = (const float*)d_in[15]; const float* b_rqk = (const float*)d_in[16];
  const float* W_rqv = (const float*)d_in[17]; const float* b_rqv = (const float*)d_in[18];

  float* ws = (float*)d_ws;
  float* lk_out = ws;                                   // 43008
  float* rq_out = ws + 43008;                           // 79872
  float* LbufN  = ws + 122880;                          // 1956864 (12*2912*56)
  float* Rbuf   = ws + 2079744;                         // 3634176
  unsigned short* vb2 = (unsigned short*)(ws + 5713920);// 2752512 shorts
  float* ql     = ws + 7090176;                         // 43008
  float* qr     = ws + 7133184;                         // 79872
  // Klg/Krg alias the LbufN/Rbuf space (dead before k_midg writes them)
  float* Klg = LbufN;                                   // 2236416
  float* Krg = LbufN + 2236416;                         // 2236416 (ends < Rbuf end)

  k_proj<<<1140, 256, 0, stream>>>(lk, rq, cosb, sinb,
      W_lkk, b_lkk, W_rqk, b_rqk, W_lkq, b_lkq, W_rqq, b_rqq,
      Klg, Krg, ql, qr);
  k_sv<<<2592, 256, 0, stream>>>(lk, rq, v, cosb, sinb, Klg, Krg, ql, qr,
      W_lkv, b_lkv, W_rqv, b_rqv, lk_out, rq_out, vb2);
  k_midg<<<1644, 256, 0, stream>>>(lq, rk, lk_out, rq_out, cosb, sinb, LbufN, Rbuf);
  k_main<<<1248, 256, 0, stream>>>(LbufN, Rbuf, vb2, (float*)d_out);
}